// Round 7
// baseline (22.665 us; speedup 1.0000x reference)
//
#include <hip/hip_runtime.h>

// Problem constants (from reference)
#define V_SZ 100000
#define D_SZ 128
#define B_SZ 4096
#define NEG_SZ 5
#define L_SZ 6

__device__ __forceinline__ float log_sigmoid(float x) {
    // stable: log_sigmoid(x) = min(x,0) - log(1 + exp(-|x|))
    // fast hw transcendentals: error ~1e-6, far under the 8e-2 threshold
    return fminf(x, 0.0f) - __logf(1.0f + __expf(-fabsf(x)));
}

// ONE WAVE per batch element b (grid = B/4 = 1024 blocks, 4 waves each).
// Each wave pools all 7 phrases of its b entirely in registers:
//   phrase p=0 -> embed_u (u table), p=1 -> embed_v, p=2..6 -> negs 0..4.
//   Gathers are float4 (16B/lane): lanes 0-31 fetch item 2j, lanes 32-63
//   item 2j+1 -> 3 gathers per phrase, 21 independent gathers in flight.
// All gathers unconditional (padding indices are valid vocab ids); ragged
// mask applied at accumulation. After the cross-half shfl_xor(32) combine,
// every lane holds 4 dims of each pooled vector (halves identical) -> the 6
// dots are 32-lane shuffle reduces. No LDS, no barrier, no idle waves.
template <bool ATOMIC>
__global__ __launch_bounds__(256, 4) void skipgram_loss_kernel(
    const float* __restrict__ u_emb,
    const float* __restrict__ v_emb,
    const int* __restrict__ pos_u_idx,
    const int* __restrict__ pos_u_len,
    const int* __restrict__ pos_v_idx,
    const int* __restrict__ pos_v_len,
    const int* __restrict__ neg_v_idx,
    const int* __restrict__ neg_v_len,
    float* __restrict__ out)   // per_b[B] if !ATOMIC, else scalar accum
{
    const int wave = threadIdx.x >> 6;
    const int lane = threadIdx.x & 63;
    const int b    = blockIdx.x * 4 + wave;
    const int half = lane >> 5;          // 0: items 0,2,4 ; 1: items 1,3,5
    const int dof  = (lane & 31) * 4;    // 4 dims per lane within a row

    // ---- lengths (wave-uniform -> SGPR) ----
    int n[7];
    n[0] = __builtin_amdgcn_readfirstlane(pos_u_len[b] + 1);
    n[1] = __builtin_amdgcn_readfirstlane(pos_v_len[b] + 1);
    #pragma unroll
    for (int k = 0; k < NEG_SZ; ++k)
        n[2 + k] = __builtin_amdgcn_readfirstlane(neg_v_len[b * NEG_SZ + k] + 1);

    // ---- all 42 indices (wave-uniform -> SGPR, issue early) ----
    int id[7][L_SZ];
    #pragma unroll
    for (int l = 0; l < L_SZ; ++l)
        id[0][l] = __builtin_amdgcn_readfirstlane(pos_u_idx[b * L_SZ + l]);
    #pragma unroll
    for (int l = 0; l < L_SZ; ++l)
        id[1][l] = __builtin_amdgcn_readfirstlane(pos_v_idx[b * L_SZ + l]);
    #pragma unroll
    for (int k = 0; k < NEG_SZ; ++k)
        #pragma unroll
        for (int l = 0; l < L_SZ; ++l)
            id[2 + k][l] = __builtin_amdgcn_readfirstlane(
                neg_v_idx[(b * NEG_SZ + k) * L_SZ + l]);

    // ---- 21 unconditional float4 row-gathers (2 rows per instruction) ----
    float4 r[7][3];
    #pragma unroll
    for (int p = 0; p < 7; ++p) {
        const float* t = (p == 0) ? u_emb : v_emb;
        #pragma unroll
        for (int j = 0; j < 3; ++j) {
            const int idx = half ? id[p][2 * j + 1] : id[p][2 * j];
            r[p][j] = *reinterpret_cast<const float4*>(
                &t[(size_t)idx * D_SZ + dof]);
        }
    }

    // ---- masked accumulate, combine halves, scale (all in-register) ----
    float4 a[7];
    #pragma unroll
    for (int p = 0; p < 7; ++p) {
        float4 acc = make_float4(0.f, 0.f, 0.f, 0.f);
        #pragma unroll
        for (int j = 0; j < 3; ++j) {
            const bool valid = (2 * j + half) < n[p];
            acc.x += valid ? r[p][j].x : 0.f;
            acc.y += valid ? r[p][j].y : 0.f;
            acc.z += valid ? r[p][j].z : 0.f;
            acc.w += valid ? r[p][j].w : 0.f;
        }
        acc.x += __shfl_xor(acc.x, 32);
        acc.y += __shfl_xor(acc.y, 32);
        acc.z += __shfl_xor(acc.z, 32);
        acc.w += __shfl_xor(acc.w, 32);
        const float inv = 1.0f / (float)n[p];
        acc.x *= inv; acc.y *= inv; acc.z *= inv; acc.w *= inv;
        a[p] = acc;   // lanes 0-31 and 32-63 hold identical copies
    }

    // ---- 6 dots: per-lane 4-dim partials, 32-lane shuffle reduce ----
    float s[6];
    #pragma unroll
    for (int k = 0; k < 6; ++k)
        s[k] = a[0].x * a[k + 1].x + a[0].y * a[k + 1].y +
               a[0].z * a[k + 1].z + a[0].w * a[k + 1].w;
    #pragma unroll
    for (int k = 0; k < 6; ++k)
        #pragma unroll
        for (int off = 16; off > 0; off >>= 1)
            s[k] += __shfl_xor(s[k], off);

    if (lane == 0) {
        float loss = log_sigmoid(s[0]);           // positive pair
        #pragma unroll
        for (int k = 1; k < 6; ++k) loss += log_sigmoid(-s[k]);
        if (ATOMIC) atomicAdd(out, -loss / (float)B_SZ);
        else        out[b] = loss;
    }
}

__global__ __launch_bounds__(256) void skipgram_reduce_kernel(
    const float* __restrict__ per_b, float* __restrict__ out)
{
    __shared__ float s[4];
    // 4096 floats = 1024 float4 = 4 float4 per thread, fully unrolled
    float acc = 0.0f;
    #pragma unroll
    for (int i = 0; i < 4; ++i) {
        const float4 v = reinterpret_cast<const float4*>(per_b)[
            i * 256 + threadIdx.x];
        acc += (v.x + v.y) + (v.z + v.w);
    }
    #pragma unroll
    for (int off = 32; off > 0; off >>= 1) acc += __shfl_xor(acc, off);
    const int wave = threadIdx.x >> 6;
    const int lane = threadIdx.x & 63;
    if (lane == 0) s[wave] = acc;
    __syncthreads();
    if (threadIdx.x == 0) {
        out[0] = -(s[0] + s[1] + s[2] + s[3]) / (float)B_SZ;
    }
}

extern "C" void kernel_launch(void* const* d_in, const int* in_sizes, int n_in,
                              void* d_out, int out_size, void* d_ws, size_t ws_size,
                              hipStream_t stream) {
    const float* u_emb     = (const float*)d_in[0];
    const float* v_emb     = (const float*)d_in[1];
    const int*   pos_u_idx = (const int*)d_in[2];
    const int*   pos_u_len = (const int*)d_in[3];
    const int*   pos_v_idx = (const int*)d_in[4];
    const int*   pos_v_len = (const int*)d_in[5];
    const int*   neg_v_idx = (const int*)d_in[6];
    const int*   neg_v_len = (const int*)d_in[7];
    float* out = (float*)d_out;

    if (ws_size >= (size_t)B_SZ * sizeof(float)) {
        float* per_b = (float*)d_ws;
        skipgram_loss_kernel<false><<<B_SZ / 4, 256, 0, stream>>>(
            u_emb, v_emb, pos_u_idx, pos_u_len, pos_v_idx, pos_v_len,
            neg_v_idx, neg_v_len, per_b);
        skipgram_reduce_kernel<<<1, 256, 0, stream>>>(per_b, out);
    } else {
        hipMemsetAsync(d_out, 0, sizeof(float), stream);
        skipgram_loss_kernel<true><<<B_SZ / 4, 256, 0, stream>>>(
            u_emb, v_emb, pos_u_idx, pos_u_len, pos_v_idx, pos_v_len,
            neg_v_idx, neg_v_len, out);
    }
}